// Round 18
// baseline (222.574 us; speedup 1.0000x reference)
//
#include <hip/hip_runtime.h>
#include <hip/hip_bf16.h>

// DecLayer: h_V(4,2048,128) h_E(4,2048,48,384) f32 -> out(4,2048,128) f32
// ws layout (bytes): [0, 425984) bf16 weights (w1f,w2f,w3f,wf1g,wf2g all MFMA-fragment-order)
//                    [425984, 4620288) V1 f32 [8192][128]
//                    [4620288, 8814592) h (post-LN1) f32 [8192][128]

typedef __bf16 bf16x8 __attribute__((ext_vector_type(8)));
typedef __bf16 bf16x4 __attribute__((ext_vector_type(4)));
typedef float f32x4 __attribute__((ext_vector_type(4)));

#define HH 128
#define EE 384
#define KK 48

__device__ __forceinline__ float gelu_f(float x) {
  float x2 = x * x;
  float u = x * (-1.5957691216f - 0.0713548163f * x2);
  float e = __expf(u);
  return __fdividef(x, 1.0f + e);
}

__device__ __forceinline__ bf16x8 cvt8v(f32x4 a, f32x4 b) {
  bf16x8 r;
  #pragma unroll
  for (int i = 0; i < 4; ++i) { r[i] = (__bf16)a[i]; r[i + 4] = (__bf16)b[i]; }
  return r;
}

__device__ __forceinline__ f32x4 mfma16(bf16x8 a, bf16x8 b, f32x4 c) {
  return __builtin_amdgcn_mfma_f32_16x16x32_bf16(a, b, c, 0, 0, 0);
}

__device__ __forceinline__ void gload16(const void* g, void* l) {
  __builtin_amdgcn_global_load_lds(
      (const __attribute__((address_space(1))) void*)g,
      (__attribute__((address_space(3))) void*)l, 16, 0, 0);
}

// ---------------- weight prep: ALL weights in MFMA-fragment order ----------------
__global__ void prep_kernel(const float* __restrict__ w1, const float* __restrict__ w2,
                            const float* __restrict__ w3, const float* __restrict__ wf1,
                            const float* __restrict__ wf2, __bf16* __restrict__ out) {
  int idx = blockIdx.x * 256 + threadIdx.x;
  if (idx < 49152) {                       // w1f (edge part of w1: rows 128..511)
    int t = idx & 7, lane = (idx >> 3) & 63, n = (idx >> 9) & 7, kc = idx >> 12;
    int e = kc * 32 + (lane >> 4) * 8 + t, h = n * 16 + (lane & 15);
    out[idx] = (__bf16)w1[(128 + e) * 128 + h];
  } else if (idx < 65536) {                // w2f
    int u = idx - 49152;
    int t = u & 7, lane = (u >> 3) & 63, n = (u >> 9) & 7, kc = u >> 12;
    int e = kc * 32 + (lane >> 4) * 8 + t, h = n * 16 + (lane & 15);
    out[idx] = (__bf16)w2[e * 128 + h];
  } else if (idx < 81920) {                // w3f
    int u = idx - 65536;
    int t = u & 7, lane = (u >> 3) & 63, n = (u >> 9) & 7, kc = u >> 12;
    int e = kc * 32 + (lane >> 4) * 8 + t, h = n * 16 + (lane & 15);
    out[idx] = (__bf16)w3[e * 128 + h];
  } else if (idx < 147456) {               // wf1g (fragment order)
    int u = idx - 81920;
    int t = u & 7, lane = (u >> 3) & 63, n = (u >> 9) & 7, kc = (u >> 12) & 3, w = u >> 14;
    int f = w * 128 + n * 16 + (lane & 15), h = kc * 32 + (lane >> 4) * 8 + t;
    out[idx] = (__bf16)wf1[h * 512 + f];
  } else if (idx < 212992) {               // wf2g (fragment order)
    int u = idx - 147456;
    int t = u & 7, lane = (u >> 3) & 63, n = (u >> 9) & 1, kc = (u >> 10) & 15, w = u >> 14;
    int j = w * 32 + n * 16 + (lane & 15), f = kc * 32 + (lane >> 4) * 8 + t;
    out[idx] = (__bf16)wf2[f * 128 + j];
  }
}

// ---------------- V1[p][h] = b1[h] + sum_i h_V[p][i] * w1[i][h] ----------------
__global__ __launch_bounds__(128) void v1_kernel(const float* __restrict__ hV,
                                                 const float* __restrict__ w1,
                                                 const float* __restrict__ b1,
                                                 float* __restrict__ V1) {
  __shared__ __align__(16) float sV[16][128];
  const int tid = threadIdx.x;
  const long p0 = (long)blockIdx.x * 16;
  for (int i = 0; i < 16; ++i) sV[i][tid] = hV[(p0 + i) * HH + tid];
  __syncthreads();
  float acc[16];
  float bb = b1[tid];
  #pragma unroll
  for (int p = 0; p < 16; ++p) acc[p] = bb;
  for (int k = 0; k < 128; k += 4) {
    float wa = w1[(k + 0) * HH + tid];
    float wb = w1[(k + 1) * HH + tid];
    float wc = w1[(k + 2) * HH + tid];
    float wd = w1[(k + 3) * HH + tid];
    #pragma unroll
    for (int p = 0; p < 16; ++p) {
      float4 h4 = *(const float4*)&sV[p][k];
      acc[p] = fmaf(h4.x, wa, fmaf(h4.y, wb, fmaf(h4.z, wc, fmaf(h4.w, wd, acc[p]))));
    }
  }
  #pragma unroll
  for (int p = 0; p < 16; ++p) V1[(p0 + p) * HH + tid] = acc[p];
}

// ---------------- cooperative message kernel: 1 position per block, BIG chunks ------------
// 4 waves; wave w owns output cols [w*32, w*32+32). A (48x384 f32) staged cooperatively in
// 3 x 24KB buffers, ONE buffer per 128-col chunk (4 ksteps) -> only 3 lockstep stalls in
// GEMM1 (vs 6 in R12), each stage has >= 1 full big-chunk of lead. Counted-vmcnt FIFO
// ledger hand-derived (see comments). h1/h2 reuse buf0 (48 x 256B bf16). 2 blocks/CU.
__global__ __launch_bounds__(256, 2) void msg_kernel(
    const float* __restrict__ hE, const float* __restrict__ hV,
    const float* __restrict__ maskE,
    const __bf16* __restrict__ w1f, const __bf16* __restrict__ w2f,
    const __bf16* __restrict__ w3f, const float* __restrict__ V1,
    const float* __restrict__ b2, const float* __restrict__ b3,
    const float* __restrict__ g1, const float* __restrict__ bn1,
    float* __restrict__ outH) {
  __shared__ __align__(16) char sBuf[3][24576];
  __shared__ __align__(16) float sBias[512];   // b2 | b3 | g1 | bn1
  __shared__ __align__(16) float sPart[4][2];  // LN partial (sum, sumsq) per wave

  const int tid = threadIdx.x;
  const int lane = tid & 63;
  const int w = tid >> 6;
  const int fr = lane & 15;
  const int fg = lane >> 4;
  const long p = blockIdx.x;

  for (int j = tid; j < 512; j += 256) {
    float v;
    if (j < 128) v = b2[j];
    else if (j < 256) v = b3[j - 128];
    else if (j < 384) v = g1[j - 256];
    else v = bn1[j - 384];
    sBias[j] = v;
  }
  __syncthreads();   // drains everything; ledger starts clean

  // masks: 3 vmem (oldest in queue)
  const float mk0 = maskE[p * KK + fr];
  const float mk1 = maskE[p * KK + 16 + fr];
  const float mk2 = maskE[p * KK + 32 + fr];

  // A staging: wave w owns rows [w*12, w*12+12); 6 gload16 per chunk, each covers 2 rows
  // (lane l -> row +（l>>5), granule (l&31), source granule XOR'd by (row&7) for bank-free reads)
  const char* hEp = (const char*)(hE + p * (long)(KK * EE));
  const int rhalf = lane >> 5;                 // 0..1
  const int gcol = (lane & 31) * 16;
  const char* srcR[6];
  int dstR[6];
  #pragma unroll
  for (int g = 0; g < 6; ++g) {
    int row = w * 12 + 2 * g + rhalf;
    srcR[g] = hEp + row * 1536 + (gcol ^ ((row & 7) << 4));
    dstR[g] = (w * 12 + 2 * g) * 512;
  }

  const __bf16* b1base = w1f + (2 * w) * 512 + lane * 8;
  const __bf16* b2base = w2f + (2 * w) * 512 + lane * 8;
  const __bf16* b3base = w3f + (2 * w) * 512 + lane * 8;

  const int aswz = (fr & 7) << 4;      // 16B-granule swizzle (rows fr,16+fr,32+fr all = fr mod 8)
  const int hswz = (fr & 7) << 4;      // bf16 h swizzle (256B rows)
  char* hB = &sBuf[0][0];

  f32x4 acc[3][2];
  #pragma unroll
  for (int m = 0; m < 3; ++m)
    #pragma unroll
    for (int n = 0; n < 2; ++n) acc[m][n] = (f32x4){0.f, 0.f, 0.f, 0.f};

  bf16x8 Bs0[2], Bs1[2], Bs2[2], Bs3[2];

#define STAGE(C, BUF) { \
    _Pragma("unroll") for (int g_ = 0; g_ < 6; ++g_) \
      gload16(srcR[g_] + (C) * 512, &sBuf[BUF][0] + dstR[g_]); }
#define LOADB(SET, BASE, KC) { \
    SET[0] = *(const bf16x8*)((BASE) + (KC) * 4096); \
    SET[1] = *(const bf16x8*)((BASE) + (KC) * 4096 + 256); }
#define WAITV(N) asm volatile("s_waitcnt vmcnt(" #N ")" ::: "memory")
#define BAR      asm volatile("s_barrier" ::: "memory")
#define BARL     asm volatile("s_waitcnt lgkmcnt(0)\ns_barrier" ::: "memory")

#define KSTEP(BUF, KS, SET) { \
    const char* rb_ = &sBuf[BUF][0]; \
    const int cb0_ = ((KS) * 128 + fg * 32) ^ aswz; \
    const int cb1_ = ((KS) * 128 + fg * 32 + 16) ^ aswz; \
    f32x4 x0_ = *(const f32x4*)(rb_ + fr * 512 + cb0_); \
    f32x4 x1_ = *(const f32x4*)(rb_ + fr * 512 + cb1_); \
    f32x4 x2_ = *(const f32x4*)(rb_ + (16 + fr) * 512 + cb0_); \
    f32x4 x3_ = *(const f32x4*)(rb_ + (16 + fr) * 512 + cb1_); \
    f32x4 x4_ = *(const f32x4*)(rb_ + (32 + fr) * 512 + cb0_); \
    f32x4 x5_ = *(const f32x4*)(rb_ + (32 + fr) * 512 + cb1_); \
    bf16x8 af0 = cvt8v(x0_, x1_); \
    bf16x8 af1 = cvt8v(x2_, x3_); \
    bf16x8 af2 = cvt8v(x4_, x5_); \
    acc[0][0] = mfma16(SET[0], af0, acc[0][0]); acc[0][1] = mfma16(SET[1], af0, acc[0][1]); \
    acc[1][0] = mfma16(SET[0], af1, acc[1][0]); acc[1][1] = mfma16(SET[1], af1, acc[1][1]); \
    acc[2][0] = mfma16(SET[0], af2, acc[2][0]); acc[2][1] = mfma16(SET[1], af2, acc[2][1]); }

#define KSTEPH(KS, SET) { \
    const int cb_ = ((KS) * 64 + fg * 16) ^ hswz; \
    bf16x8 af0 = *(const bf16x8*)(hB + fr * 256 + cb_); \
    bf16x8 af1 = *(const bf16x8*)(hB + (16 + fr) * 256 + cb_); \
    bf16x8 af2 = *(const bf16x8*)(hB + (32 + fr) * 256 + cb_); \
    acc[0][0] = mfma16(SET[0], af0, acc[0][0]); acc[0][1] = mfma16(SET[1], af0, acc[0][1]); \
    acc[1][0] = mfma16(SET[0], af1, acc[1][0]); acc[1][1] = mfma16(SET[1], af1, acc[1][1]); \
    acc[2][0] = mfma16(SET[0], af2, acc[2][0]); acc[2][1] = mfma16(SET[1], af2, acc[2][1]); }

#define EPI(BQ0, BQ1) { \
    _Pragma("unroll") for (int m_ = 0; m_ < 3; ++m_) { \
      const int rb_ = (m_ * 16 + fr) * 256; \
      { bf16x4 t_; \
        _Pragma("unroll") for (int j_ = 0; j_ < 4; ++j_) t_[j_] = (__bf16)gelu_f(acc[m_][0][j_] + BQ0[j_]); \
        *(bf16x4*)(hB + rb_ + (((2 * w) * 32 + fg * 8) ^ hswz)) = t_; \
        acc[m_][0] = (f32x4){0.f, 0.f, 0.f, 0.f}; } \
      { bf16x4 t_; \
        _Pragma("unroll") for (int j_ = 0; j_ < 4; ++j_) t_[j_] = (__bf16)gelu_f(acc[m_][1][j_] + BQ1[j_]); \
        *(bf16x4*)(hB + rb_ + (((2 * w + 1) * 32 + fg * 8) ^ hswz)) = t_; \
        acc[m_][1] = (f32x4){0.f, 0.f, 0.f, 0.f}; } } }

  // ---- prologue: [M(3)] S0(6) B0..B3(8) S1(6) = 23 outstanding ----
  STAGE(0, 0);
  LOADB(Bs0, b1base, 0);
  LOADB(Bs1, b1base, 1);
  LOADB(Bs2, b1base, 2);
  LOADB(Bs3, b1base, 3);
  STAGE(1, 1);

  f32x4 vq0, vq1, hq0, hq1;

  // ---- GEMM1: 3 big chunks (4 ksteps each) ----
  WAITV(6); BAR;   // c0: needs M,S0,B0-3 -> leaves S1(6)
  KSTEP(0, 0, Bs0); LOADB(Bs0, b1base, 4);
  KSTEP(0, 1, Bs1); LOADB(Bs1, b1base, 5);
  KSTEP(0, 2, Bs2); LOADB(Bs2, b1base, 6);
  KSTEP(0, 3, Bs3); LOADB(Bs3, b1base, 7);
  STAGE(2, 2);

  WAITV(6); BAR;   // c1: needs S1,B4-7 -> leaves S2(6)
  KSTEP(1, 0, Bs0); LOADB(Bs0, b1base, 8);
  KSTEP(1, 1, Bs1); LOADB(Bs1, b1base, 9);
  KSTEP(1, 2, Bs2); LOADB(Bs2, b1base, 10);
  KSTEP(1, 3, Bs3); LOADB(Bs3, b1base, 11);
  vq0 = *(const f32x4*)(V1 + p * HH + (2 * w) * 16 + fg * 4);
  vq1 = *(const f32x4*)(V1 + p * HH + (2 * w + 1) * 16 + fg * 4);

  WAITV(2); BAR;   // c2: needs S2,B8-11 -> leaves vq(2)
  KSTEP(2, 0, Bs0); LOADB(Bs0, b2base, 0);       // G2 kc0 -> s0
  KSTEP(2, 1, Bs1); LOADB(Bs1, b2base, 1);       // G2 kc1 -> s1
  KSTEP(2, 2, Bs2); LOADB(Bs2, b2base, 2);       // G2 kc2 -> s2
  KSTEP(2, 3, Bs3); LOADB(Bs3, b2base, 3);       // G2 kc3 -> s3

  // ---- EPI1: + V1 (has b1), gelu -> h1 (buf0); G2 B0..3 stay in flight ----
  WAITV(8);        // drains vq only
  EPI(vq0, vq1);
  BARL;            // h1 visible to all waves

  // ---- GEMM2: h1(48x128) @ w2 ----
  WAITV(6);
  KSTEPH(0, Bs0); LOADB(Bs0, b3base, 0);         // G3 kc0 -> s0
  WAITV(6);
  KSTEPH(1, Bs1); LOADB(Bs1, b3base, 1);         // G3 kc1 -> s1
  WAITV(6);
  KSTEPH(2, Bs2); LOADB(Bs2, b3base, 2);         // G3 kc2 -> s2
  WAITV(6);
  KSTEPH(3, Bs3); LOADB(Bs3, b3base, 3);         // G3 kc3 -> s3
  BARL;            // all GEMM2 reads done
  {
    f32x4 bq0 = *(const f32x4*)(&sBias[(2 * w) * 16 + fg * 4]);
    f32x4 bq1 = *(const f32x4*)(&sBias[(2 * w + 1) * 16 + fg * 4]);
    EPI(bq0, bq1);
  }
  BARL;            // h2 visible

  // ---- GEMM3: h2(48x128) @ w3 ----
  WAITV(6);
  KSTEPH(0, Bs0);
  hq0 = *(const f32x4*)(hV + p * HH + (2 * w) * 16 + fg * 4);
  hq1 = *(const f32x4*)(hV + p * HH + (2 * w + 1) * 16 + fg * 4);
  WAITV(6);
  KSTEPH(1, Bs1);
  WAITV(4);
  KSTEPH(2, Bs2);
  WAITV(2);
  KSTEPH(3, Bs3);

  // ---- masked K-reduction over rows (in-register, shfl over fr bits) ----
  f32x4 red[2];
  {
    #pragma unroll
    for (int n = 0; n < 2; ++n) {
      f32x4 bq = *(const f32x4*)(&sBias[128 + (2 * w + n) * 16 + fg * 4]);
      red[n] = mk0 * (acc[0][n] + bq) + mk1 * (acc[1][n] + bq) + mk2 * (acc[2][n] + bq);
    }
    #pragma unroll
    for (int off = 1; off <= 8; off <<= 1)
      #pragma unroll
      for (int n = 0; n < 2; ++n)
        #pragma unroll
        for (int j = 0; j < 4; ++j)
          red[n][j] += __shfl_xor(red[n][j], off);
  }

  // ---- LN1 (cross-wave: single-pass sum / sumsq partials) ----
  WAITV(0);   // hq ready
  {
    f32x4 xq[2];
    xq[0] = hq0 + red[0] * (1.f / 30.f);
    xq[1] = hq1 + red[1] * (1.f / 30.f);
    float s = 0.f, t = 0.f;
    #pragma unroll
    for (int n = 0; n < 2; ++n)
      #pragma unroll
      for (int j = 0; j < 4; ++j) { float x = xq[n][j]; s += x; t += x * x; }
    s += __shfl_xor(s, 16); s += __shfl_xor(s, 32);
    t += __shfl_xor(t, 16); t += __shfl_xor(t, 32);
    if (lane == 0) { sPart[w][0] = s; sPart[w][1] = t; }
    BARL;
    float S = sPart[0][0] + sPart[1][0] + sPart[2][0] + sPart[3][0];
    float T = sPart[0][1] + sPart[1][1] + sPart[2][1] + sPart[3][1];
    float mean = S * (1.f / 128.f);
    float var = T * (1.f / 128.f) - mean * mean;
    float rs = rsqrtf(var + 1e-5f);
    if (fr == 0) {
      #pragma unroll
      for (int n = 0; n < 2; ++n) {
        f32x4 gq = *(const f32x4*)(&sBias[256 + (2 * w + n) * 16 + fg * 4]);
        f32x4 bq = *(const f32x4*)(&sBias[384 + (2 * w + n) * 16 + fg * 4]);
        f32x4 o;
        #pragma unroll
        for (int j = 0; j < 4; ++j) o[j] = (xq[n][j] - mean) * rs * gq[j] + bq[j];
        *(f32x4*)(outH + p * HH + (2 * w + n) * 16 + fg * 4) = o;
      }
    }
  }
#undef STAGE
#undef LOADB
#undef WAITV
#undef BAR
#undef BARL
#undef KSTEP
#undef KSTEPH
#undef EPI
}

// ---------------- FFN + LN2 + mask (16-row tiles, fragment-ordered weights) ----------------
__global__ __launch_bounds__(256, 2) void ffn_kernel(
    const float* __restrict__ xin, const __bf16* __restrict__ wf1g,
    const float* __restrict__ bf1, const __bf16* __restrict__ wf2g,
    const float* __restrict__ bf2, const float* __restrict__ g2,
    const float* __restrict__ bn2, const float* __restrict__ maskV,
    float* __restrict__ out) {
  __shared__ __align__(16) __bf16 sX[16][136];
  __shared__ __align__(16) __bf16 sH1[16][520];
  __shared__ __align__(16) float sOut[16][132];
  const int tid = threadIdx.x, lane = tid & 63, w = tid >> 6;
  const long row0 = (long)blockIdx.x * 16;
  const int fr = lane & 15, fg = lane >> 4;
  const __bf16* bw1 = wf1g + w * 16384 + lane * 8;
  const __bf16* bw2 = wf2g + w * 16384 + lane * 8;

  {  // stage X -> bf16
    int r = tid >> 4, c = (tid & 15) * 8;
    const float* src = xin + (row0 + r) * HH + c;
    f32x4 v0 = *(const f32x4*)src, v1 = *(const f32x4*)(src + 4);
    *(bf16x8*)&sX[r][c] = cvt8v(v0, v1);
  }
  __syncthreads();

  f32x4 a1[8];
  #pragma unroll
  for (int n = 0; n < 8; ++n) a1[n] = (f32x4){0.f, 0.f, 0.f, 0.f};
  #pragma unroll
  for (int kc = 0; kc < 4; ++kc) {
    int k0 = kc * 32;
    bf16x8 af0 = *(const bf16x8*)&sX[fr][k0 + fg * 8];
    #pragma unroll
    for (int n = 0; n < 8; ++n) {
      bf16x8 bfr = *(const bf16x8*)(bw1 + (kc * 8 + n) * 512);
      a1[n] = mfma16(af0, bfr, a1[n]);
    }
  }
  #pragma unroll
  for (int n = 0; n < 8; ++n) {
    float bv = bf1[w * 128 + n * 16 + fr];
    #pragma unroll
    for (int j = 0; j < 4; ++j)
      sH1[fg * 4 + j][w * 128 + n * 16 + fr] = (__bf16)gelu_f(a1[n][j] + bv);
  }
  __syncthreads();

  f32x4 a2[2];
  #pragma unroll
  for (int n = 0; n < 2; ++n) a2[n] = (f32x4){0.f, 0.f, 0.f, 0.f};
  #pragma unroll
  for (int kc = 0; kc < 16; ++kc) {
    int k0 = kc * 32;
    bf16x8 af0 = *(const bf16x8*)&sH1[fr][k0 + fg * 8];
    #pragma unroll
    for (int n = 0; n < 2; ++n) {
      bf16x8 bfr = *(const bf16x8*)(bw2 + (kc * 2 + n) * 512);
      a2[n] = mfma16(af0, bfr, a2[n]);
    }
  }
  #pragma unroll
  for (int n = 0; n < 2; ++n) {
    float bv = bf2[w * 32 + n * 16 + fr];
    #pragma unroll
    for (int j = 0; j < 4; ++j)
      sOut[fg * 4 + j][w * 32 + n * 16 + fr] = a2[n][j] + bv;
  }
  __syncthreads();

  {
    int r = tid >> 4, c0 = (tid & 15) * 8;
    long p = row0 + r;
    const float* xp = xin + p * HH + c0;
    float x[8];
    #pragma unroll
    for (int i = 0; i < 8; ++i) x[i] = xp[i] + sOut[r][c0 + i];
    float s = 0.f;
    #pragma unroll
    for (int i = 0; i < 8; ++i) s += x[i];
    s += __shfl_xor(s, 1); s += __shfl_xor(s, 2); s += __shfl_xor(s, 4); s += __shfl_xor(s, 8);
    float mean = s * (1.f / 128.f);
    float q = 0.f;
    #pragma unroll
    for (int i = 0; i < 8; ++i) { float e = x[i] - mean; q += e * e; }
    q += __shfl_xor(q, 1); q += __shfl_xor(q, 2); q += __shfl_xor(q, 4); q += __shfl_xor(q, 8);
    float rs = rsqrtf(q * (1.f / 128.f) + 1e-5f);
    float mv = maskV[p];
    float* op = out + p * HH + c0;
    #pragma unroll
    for (int i = 0; i < 8; ++i)
      op[i] = ((x[i] - mean) * rs * g2[c0 + i] + bn2[c0 + i]) * mv;
  }
}

extern "C" void kernel_launch(void* const* d_in, const int* in_sizes, int n_in,
                              void* d_out, int out_size, void* d_ws, size_t ws_size,
                              hipStream_t stream) {
  const float* hV    = (const float*)d_in[0];
  const float* hE    = (const float*)d_in[1];
  const float* maskV = (const float*)d_in[2];
  const float* maskE = (const float*)d_in[3];
  const float* w1    = (const float*)d_in[4];
  const float* b1    = (const float*)d_in[5];
  const float* w2    = (const float*)d_in[6];
  const float* b2    = (const float*)d_in[7];
  const float* w3    = (const float*)d_in[8];
  const float* b3    = (const float*)d_in[9];
  const float* g1    = (const float*)d_in[10];
  const float* bn1   = (const float*)d_in[11];
  const float* g2    = (const float*)d_in[12];
  const float* bn2   = (const float*)d_in[13];
  const float* wf1   = (const float*)d_in[14];
  const float* bf1   = (const float*)d_in[15];
  const float* wf2   = (const float*)d_in[16];
  const float* bf2   = (const float*)d_in[17];
  float* out = (float*)d_out;

  __bf16* wsb = (__bf16*)d_ws;                           // 212992 bf16 elems
  float* V1   = (float*)((char*)d_ws + 425984);          // [8192][128] f32
  float* hbuf = (float*)((char*)d_ws + 4620288);         // [8192][128] f32
  // requires ws_size >= 8,814,592 bytes

  prep_kernel<<<832, 256, 0, stream>>>(w1, w2, w3, wf1, wf2, wsb);
  v1_kernel<<<512, 128, 0, stream>>>(hV, w1, b1, V1);
  msg_kernel<<<8192, 256, 0, stream>>>(hE, hV, maskE,
                                       wsb, wsb + 49152, wsb + 65536, V1,
                                       b2, b3, g1, bn1, hbuf);
  ffn_kernel<<<512, 256, 0, stream>>>(hbuf, wsb + 81920, bf1, wsb + 147456, bf2,
                                      g2, bn2, maskV, out);
}

// Round 19
// 199.829 us; speedup vs baseline: 1.1138x; 1.1138x over previous
//
#include <hip/hip_runtime.h>
#include <hip/hip_bf16.h>

// DecLayer: h_V(4,2048,128) h_E(4,2048,48,384) f32 -> out(4,2048,128) f32
// ws layout (bytes): [0, 425984) bf16 weights (w1f,w2f,w3f,wf1g,wf2g all MFMA-fragment-order)
//                    [425984, 4620288) V1 f32 [8192][128]
//                    [4620288, 8814592) h (post-LN1) f32 [8192][128]
// FINAL: R12/R17 configuration, verified 200.2 us (best of 18 rounds).

typedef __bf16 bf16x8 __attribute__((ext_vector_type(8)));
typedef __bf16 bf16x4 __attribute__((ext_vector_type(4)));
typedef float f32x4 __attribute__((ext_vector_type(4)));

#define HH 128
#define EE 384
#define KK 48

__device__ __forceinline__ float gelu_f(float x) {
  float x2 = x * x;
  float u = x * (-1.5957691216f - 0.0713548163f * x2);
  float e = __expf(u);
  return __fdividef(x, 1.0f + e);
}

__device__ __forceinline__ bf16x8 cvt8v(f32x4 a, f32x4 b) {
  bf16x8 r;
  #pragma unroll
  for (int i = 0; i < 4; ++i) { r[i] = (__bf16)a[i]; r[i + 4] = (__bf16)b[i]; }
  return r;
}

__device__ __forceinline__ f32x4 mfma16(bf16x8 a, bf16x8 b, f32x4 c) {
  return __builtin_amdgcn_mfma_f32_16x16x32_bf16(a, b, c, 0, 0, 0);
}

__device__ __forceinline__ void gload16(const void* g, void* l) {
  __builtin_amdgcn_global_load_lds(
      (const __attribute__((address_space(1))) void*)g,
      (__attribute__((address_space(3))) void*)l, 16, 0, 0);
}

// ---------------- weight prep: ALL weights in MFMA-fragment order ----------------
__global__ void prep_kernel(const float* __restrict__ w1, const float* __restrict__ w2,
                            const float* __restrict__ w3, const float* __restrict__ wf1,
                            const float* __restrict__ wf2, __bf16* __restrict__ out) {
  int idx = blockIdx.x * 256 + threadIdx.x;
  if (idx < 49152) {                       // w1f (edge part of w1: rows 128..511)
    int t = idx & 7, lane = (idx >> 3) & 63, n = (idx >> 9) & 7, kc = idx >> 12;
    int e = kc * 32 + (lane >> 4) * 8 + t, h = n * 16 + (lane & 15);
    out[idx] = (__bf16)w1[(128 + e) * 128 + h];
  } else if (idx < 65536) {                // w2f
    int u = idx - 49152;
    int t = u & 7, lane = (u >> 3) & 63, n = (u >> 9) & 7, kc = u >> 12;
    int e = kc * 32 + (lane >> 4) * 8 + t, h = n * 16 + (lane & 15);
    out[idx] = (__bf16)w2[e * 128 + h];
  } else if (idx < 81920) {                // w3f
    int u = idx - 65536;
    int t = u & 7, lane = (u >> 3) & 63, n = (u >> 9) & 7, kc = u >> 12;
    int e = kc * 32 + (lane >> 4) * 8 + t, h = n * 16 + (lane & 15);
    out[idx] = (__bf16)w3[e * 128 + h];
  } else if (idx < 147456) {               // wf1g (fragment order)
    int u = idx - 81920;
    int t = u & 7, lane = (u >> 3) & 63, n = (u >> 9) & 7, kc = (u >> 12) & 3, w = u >> 14;
    int f = w * 128 + n * 16 + (lane & 15), h = kc * 32 + (lane >> 4) * 8 + t;
    out[idx] = (__bf16)wf1[h * 512 + f];
  } else if (idx < 212992) {               // wf2g (fragment order)
    int u = idx - 147456;
    int t = u & 7, lane = (u >> 3) & 63, n = (u >> 9) & 1, kc = (u >> 10) & 15, w = u >> 14;
    int j = w * 32 + n * 16 + (lane & 15), f = kc * 32 + (lane >> 4) * 8 + t;
    out[idx] = (__bf16)wf2[f * 128 + j];
  }
}

// ---------------- V1[p][h] = b1[h] + sum_i h_V[p][i] * w1[i][h] ----------------
__global__ __launch_bounds__(128) void v1_kernel(const float* __restrict__ hV,
                                                 const float* __restrict__ w1,
                                                 const float* __restrict__ b1,
                                                 float* __restrict__ V1) {
  __shared__ __align__(16) float sV[16][128];
  const int tid = threadIdx.x;
  const long p0 = (long)blockIdx.x * 16;
  for (int i = 0; i < 16; ++i) sV[i][tid] = hV[(p0 + i) * HH + tid];
  __syncthreads();
  float acc[16];
  float bb = b1[tid];
  #pragma unroll
  for (int p = 0; p < 16; ++p) acc[p] = bb;
  for (int k = 0; k < 128; k += 4) {
    float wa = w1[(k + 0) * HH + tid];
    float wb = w1[(k + 1) * HH + tid];
    float wc = w1[(k + 2) * HH + tid];
    float wd = w1[(k + 3) * HH + tid];
    #pragma unroll
    for (int p = 0; p < 16; ++p) {
      float4 h4 = *(const float4*)&sV[p][k];
      acc[p] = fmaf(h4.x, wa, fmaf(h4.y, wb, fmaf(h4.z, wc, fmaf(h4.w, wd, acc[p]))));
    }
  }
  #pragma unroll
  for (int p = 0; p < 16; ++p) V1[(p0 + p) * HH + tid] = acc[p];
}

// ---------------- cooperative message kernel: 1 position per block (FINAL, 200us) ---------
// 4 waves; wave w owns output cols [w*32, w*32+32) (frags 2w, 2w+1). A (48x384 f32) staged
// cooperatively in 3 rotating 12KB LDS buffers (6 chunks of 64 cols); raw s_barrier per chunk
// + counted vmcnt (batch ledger: every chunk entry needs the batch-before-last -> W(7) steady).
// After GEMM1, buf0 is reused as the 48x128 bf16 h buffer. 4 B-register sets rotate kc%4.
__global__ __launch_bounds__(256, 4) void msg_kernel(
    const float* __restrict__ hE, const float* __restrict__ hV,
    const float* __restrict__ maskE,
    const __bf16* __restrict__ w1f, const __bf16* __restrict__ w2f,
    const __bf16* __restrict__ w3f, const float* __restrict__ V1,
    const float* __restrict__ b2, const float* __restrict__ b3,
    const float* __restrict__ g1, const float* __restrict__ bn1,
    float* __restrict__ outH) {
  __shared__ __align__(16) char sBuf[3][12288];
  __shared__ __align__(16) float sBias[512];   // b2 | b3 | g1 | bn1
  __shared__ __align__(16) float sPart[4][2];  // LN partial (sum, sumsq) per wave

  const int tid = threadIdx.x;
  const int lane = tid & 63;
  const int w = tid >> 6;
  const int fr = lane & 15;
  const int fg = lane >> 4;
  const long p = blockIdx.x;

  for (int j = tid; j < 512; j += 256) {
    float v;
    if (j < 128) v = b2[j];
    else if (j < 256) v = b3[j - 128];
    else if (j < 384) v = g1[j - 256];
    else v = bn1[j - 384];
    sBias[j] = v;
  }
  __syncthreads();   // drains everything; ledger starts clean

  // masks: 3 vmem (oldest in queue)
  const float mk0 = maskE[p * KK + fr];
  const float mk1 = maskE[p * KK + 16 + fr];
  const float mk2 = maskE[p * KK + 32 + fr];

  // A staging: per wave 3 gload16 per chunk; 4 rows x 256B per gload, source pre-swizzled
  const char* hEp = (const char*)(hE + p * (long)(KK * EE));
  const int lrow = lane >> 4;          // 0..3
  const int lcb = (lane & 15) * 16;
  const int r0 = (w * 3 + 0) * 4 + lrow;
  const int r1 = (w * 3 + 1) * 4 + lrow;
  const int r2 = (w * 3 + 2) * 4 + lrow;
  const char* srcA0 = hEp + r0 * 1536 + (lcb ^ ((r0 & 7) << 5));
  const char* srcA1 = hEp + r1 * 1536 + (lcb ^ ((r1 & 7) << 5));
  const char* srcA2 = hEp + r2 * 1536 + (lcb ^ ((r2 & 7) << 5));
  const int dst0 = (w * 3 + 0) * 1024;
  const int dst1 = (w * 3 + 1) * 1024;
  const int dst2 = (w * 3 + 2) * 1024;

  const __bf16* b1base = w1f + (2 * w) * 512 + lane * 8;
  const __bf16* b2base = w2f + (2 * w) * 512 + lane * 8;
  const __bf16* b3base = w3f + (2 * w) * 512 + lane * 8;

  const int aswz = (fr & 7) << 5;      // f32 A-chunk swizzle (256B rows)
  const int hswz = (fr & 7) << 4;      // bf16 h swizzle (256B rows)
  char* hB = &sBuf[0][0];

  f32x4 acc[3][2];
  #pragma unroll
  for (int m = 0; m < 3; ++m)
    #pragma unroll
    for (int n = 0; n < 2; ++n) acc[m][n] = (f32x4){0.f, 0.f, 0.f, 0.f};

  bf16x8 Bs0[2], Bs1[2], Bs2[2], Bs3[2];

#define STAGE(C, BUF) { \
    gload16(srcA0 + (C) * 256, &sBuf[BUF][0] + dst0); \
    gload16(srcA1 + (C) * 256, &sBuf[BUF][0] + dst1); \
    gload16(srcA2 + (C) * 256, &sBuf[BUF][0] + dst2); }
#define LOADB(SET, BASE, KC) { \
    SET[0] = *(const bf16x8*)((BASE) + (KC) * 4096); \
    SET[1] = *(const bf16x8*)((BASE) + (KC) * 4096 + 256); }
#define WAITV(N) asm volatile("s_waitcnt vmcnt(" #N ")" ::: "memory")
#define BAR      asm volatile("s_barrier" ::: "memory")
#define BARL     asm volatile("s_waitcnt lgkmcnt(0)\ns_barrier" ::: "memory")

#define KSTEP(BUF, KS, SET) { \
    const char* rb_ = &sBuf[BUF][0]; \
    const int cb_ = ((KS) * 128 + fg * 32) ^ aswz; \
    f32x4 x0_ = *(const f32x4*)(rb_ + fr * 256 + cb_); \
    f32x4 x1_ = *(const f32x4*)(rb_ + fr * 256 + cb_ + 16); \
    f32x4 x2_ = *(const f32x4*)(rb_ + (16 + fr) * 256 + cb_); \
    f32x4 x3_ = *(const f32x4*)(rb_ + (16 + fr) * 256 + cb_ + 16); \
    f32x4 x4_ = *(const f32x4*)(rb_ + (32 + fr) * 256 + cb_); \
    f32x4 x5_ = *(const f32x4*)(rb_ + (32 + fr) * 256 + cb_ + 16); \
    bf16x8 af0 = cvt8v(x0_, x1_); \
    bf16x8 af1 = cvt8v(x2_, x3_); \
    bf16x8 af2 = cvt8v(x4_, x5_); \
    acc[0][0] = mfma16(SET[0], af0, acc[0][0]); acc[0][1] = mfma16(SET[1], af0, acc[0][1]); \
    acc[1][0] = mfma16(SET[0], af1, acc[1][0]); acc[1][1] = mfma16(SET[1], af1, acc[1][1]); \
    acc[2][0] = mfma16(SET[0], af2, acc[2][0]); acc[2][1] = mfma16(SET[1], af2, acc[2][1]); }

#define KSTEPH(KS, SET) { \
    const int cb_ = ((KS) * 64 + fg * 16) ^ hswz; \
    bf16x8 af0 = *(const bf16x8*)(hB + fr * 256 + cb_); \
    bf16x8 af1 = *(const bf16x8*)(hB + (16 + fr) * 256 + cb_); \
    bf16x8 af2 = *(const bf16x8*)(hB + (32 + fr) * 256 + cb_); \
    acc[0][0] = mfma16(SET[0], af0, acc[0][0]); acc[0][1] = mfma16(SET[1], af0, acc[0][1]); \
    acc[1][0] = mfma16(SET[0], af1, acc[1][0]); acc[1][1] = mfma16(SET[1], af1, acc[1][1]); \
    acc[2][0] = mfma16(SET[0], af2, acc[2][0]); acc[2][1] = mfma16(SET[1], af2, acc[2][1]); }

#define EPI(BQ0, BQ1) { \
    _Pragma("unroll") for (int m_ = 0; m_ < 3; ++m_) { \
      const int rb_ = (m_ * 16 + fr) * 256; \
      { bf16x4 t_; \
        _Pragma("unroll") for (int j_ = 0; j_ < 4; ++j_) t_[j_] = (__bf16)gelu_f(acc[m_][0][j_] + BQ0[j_]); \
        *(bf16x4*)(hB + rb_ + (((2 * w) * 32 + fg * 8) ^ hswz)) = t_; \
        acc[m_][0] = (f32x4){0.f, 0.f, 0.f, 0.f}; } \
      { bf16x4 t_; \
        _Pragma("unroll") for (int j_ = 0; j_ < 4; ++j_) t_[j_] = (__bf16)gelu_f(acc[m_][1][j_] + BQ1[j_]); \
        *(bf16x4*)(hB + rb_ + (((2 * w + 1) * 32 + fg * 8) ^ hswz)) = t_; \
        acc[m_][1] = (f32x4){0.f, 0.f, 0.f, 0.f}; } } }

  // ---- prologue: [M(3)] S0(3) B0(2) B1(2) S1(3) B2(2) B3(2) = 17 outstanding ----
  STAGE(0, 0);
  LOADB(Bs0, b1base, 0);
  LOADB(Bs1, b1base, 1);
  STAGE(1, 1);
  LOADB(Bs2, b1base, 2);
  LOADB(Bs3, b1base, 3);

  f32x4 vq0, vq1, hq0, hq1;

  // ---- GEMM1: 6 chunks (2 ksteps each), steady W(7) = leave the previous batch in flight ----
  WAITV(7); BAR;  // c0: kc0(s0), kc1(s1)
  KSTEP(0, 0, Bs0); LOADB(Bs0, b1base, 4);
  KSTEP(0, 1, Bs1); LOADB(Bs1, b1base, 5);
  STAGE(2, 2);

  WAITV(7); BAR;  // c1: kc2(s2), kc3(s3)
  KSTEP(1, 0, Bs2); LOADB(Bs2, b1base, 6);
  KSTEP(1, 1, Bs3); LOADB(Bs3, b1base, 7);
  STAGE(3, 0);

  WAITV(7); BAR;  // c2: kc4(s0), kc5(s1)
  KSTEP(2, 0, Bs0); LOADB(Bs0, b1base, 8);
  KSTEP(2, 1, Bs1); LOADB(Bs1, b1base, 9);
  STAGE(4, 1);

  WAITV(7); BAR;  // c3: kc6(s2), kc7(s3)
  KSTEP(0, 0, Bs2); LOADB(Bs2, b1base, 10);
  KSTEP(0, 1, Bs3); LOADB(Bs3, b1base, 11);
  STAGE(5, 2);

  WAITV(7); BAR;  // c4: kc8(s0), kc9(s1)
  KSTEP(1, 0, Bs0); LOADB(Bs0, b2base, 0);       // G2 kc0 -> s0
  vq0 = *(const f32x4*)(V1 + p * HH + (2 * w) * 16 + fg * 4);
  vq1 = *(const f32x4*)(V1 + p * HH + (2 * w + 1) * 16 + fg * 4);
  KSTEP(1, 1, Bs1); LOADB(Bs1, b2base, 1);       // G2 kc1 -> s1

  WAITV(6); BAR;  // c5: kc10(s2), kc11(s3)
  KSTEP(2, 0, Bs2); LOADB(Bs2, b2base, 2);       // G2 kc2 -> s2
  KSTEP(2, 1, Bs3); LOADB(Bs3, b2base, 3);       // G2 kc3 -> s3

  // ---- EPI1: + V1 (has b1), gelu -> h (buf0). V1 done after W(4); G2 B0..3 stay in flight ----
  WAITV(4);
  EPI(vq0, vq1);
  BARL;            // h1 visible to all waves

  // ---- GEMM2: h1(48x128) @ w2 ----
  KSTEPH(0, Bs0); LOADB(Bs0, b3base, 0);         // G3 kc0 -> s0
  KSTEPH(1, Bs1); LOADB(Bs1, b3base, 1);         // G3 kc1 -> s1
  WAITV(4);
  KSTEPH(2, Bs2); LOADB(Bs2, b3base, 2);         // G3 kc2 -> s2
  KSTEPH(3, Bs3); LOADB(Bs3, b3base, 3);         // G3 kc3 -> s3
  BARL;            // all GEMM2 reads done
  {
    f32x4 bq0 = *(const f32x4*)(&sBias[(2 * w) * 16 + fg * 4]);
    f32x4 bq1 = *(const f32x4*)(&sBias[(2 * w + 1) * 16 + fg * 4]);
    EPI(bq0, bq1);
  }
  BARL;            // h2 visible

  // ---- GEMM3: h2(48x128) @ w3 ----
  WAITV(6);
  KSTEPH(0, Bs0);
  hq0 = *(const f32x4*)(hV + p * HH + (2 * w) * 16 + fg * 4);
  hq1 = *(const f32x4*)(hV + p * HH + (2 * w + 1) * 16 + fg * 4);
  KSTEPH(1, Bs1);
  WAITV(4);
  KSTEPH(2, Bs2);
  KSTEPH(3, Bs3);

  // ---- masked K-reduction over rows (in-register, shfl over fr bits) ----
  f32x4 red[2];
  {
    #pragma unroll
    for (int n = 0; n < 2; ++n) {
      f32x4 bq = *(const f32x4*)(&sBias[128 + (2 * w + n) * 16 + fg * 4]);
      red[n] = mk0 * (acc[0][n] + bq) + mk1 * (acc[1][n] + bq) + mk2 * (acc[2][n] + bq);
    }
    #pragma unroll
    for (int off = 1; off <= 8; off <<= 1)
      #pragma unroll
      for (int n = 0; n < 2; ++n)
        #pragma unroll
        for (int j = 0; j < 4; ++j)
          red[n][j] += __shfl_xor(red[n][j], off);
  }

  // ---- LN1 (cross-wave: single-pass sum / sumsq partials) ----
  WAITV(0);   // hq ready
  {
    f32x4 xq[2];
    xq[0] = hq0 + red[0] * (1.f / 30.f);
    xq[1] = hq1 + red[1] * (1.f / 30.f);
    float s = 0.f, t = 0.f;
    #pragma unroll
    for (int n = 0; n < 2; ++n)
      #pragma unroll
      for (int j = 0; j < 4; ++j) { float x = xq[n][j]; s += x; t += x * x; }
    s += __shfl_xor(s, 16); s += __shfl_xor(s, 32);
    t += __shfl_xor(t, 16); t += __shfl_xor(t, 32);
    if (lane == 0) { sPart[w][0] = s; sPart[w][1] = t; }
    BARL;
    float S = sPart[0][0] + sPart[1][0] + sPart[2][0] + sPart[3][0];
    float T = sPart[0][1] + sPart[1][1] + sPart[2][1] + sPart[3][1];
    float mean = S * (1.f / 128.f);
    float var = T * (1.f / 128.f) - mean * mean;
    float rs = rsqrtf(var + 1e-5f);
    if (fr == 0) {
      #pragma unroll
      for (int n = 0; n < 2; ++n) {
        f32x4 gq = *(const f32x4*)(&sBias[256 + (2 * w + n) * 16 + fg * 4]);
        f32x4 bq = *(const f32x4*)(&sBias[384 + (2 * w + n) * 16 + fg * 4]);
        f32x4 o;
        #pragma unroll
        for (int j = 0; j < 4; ++j) o[j] = (xq[n][j] - mean) * rs * gq[j] + bq[j];
        *(f32x4*)(outH + p * HH + (2 * w + n) * 16 + fg * 4) = o;
      }
    }
  }
#undef STAGE
#undef LOADB
#undef WAITV
#undef BAR
#undef BARL
#undef KSTEP
#undef KSTEPH
#undef EPI
}

// ---------------- FFN + LN2 + mask (16-row tiles, fragment-ordered weights) ----------------
__global__ __launch_bounds__(256, 2) void ffn_kernel(
    const float* __restrict__ xin, const __bf16* __restrict__ wf1g,
    const float* __restrict__ bf1, const __bf16* __restrict__ wf2g,
    const float* __restrict__ bf2, const float* __restrict__ g2,
    const float* __restrict__ bn2, const float* __restrict__ maskV,
    float* __restrict__ out) {
  __shared__ __align__(16) __bf16 sX[16][136];
  __shared__ __align__(16) __bf16 sH1[16][520];
  __shared__ __align__(16) float sOut[16][132];
  const int tid = threadIdx.x, lane = tid & 63, w = tid >> 6;
  const long row0 = (long)blockIdx.x * 16;
  const int fr = lane & 15, fg = lane >> 4;
  const __bf16* bw1 = wf1g + w * 16384 + lane * 8;
  const __bf16* bw2 = wf2g + w * 16384 + lane * 8;

  {  // stage X -> bf16
    int r = tid >> 4, c = (tid & 15) * 8;
    const float* src = xin + (row0 + r) * HH + c;
    f32x4 v0 = *(const f32x4*)src, v1 = *(const f32x4*)(src + 4);
    *(bf16x8*)&sX[r][c] = cvt8v(v0, v1);
  }
  __syncthreads();

  f32x4 a1[8];
  #pragma unroll
  for (int n = 0; n < 8; ++n) a1[n] = (f32x4){0.f, 0.f, 0.f, 0.f};
  #pragma unroll
  for (int kc = 0; kc < 4; ++kc) {
    int k0 = kc * 32;
    bf16x8 af0 = *(const bf16x8*)&sX[fr][k0 + fg * 8];
    #pragma unroll
    for (int n = 0; n < 8; ++n) {
      bf16x8 bfr = *(const bf16x8*)(bw1 + (kc * 8 + n) * 512);
      a1[n] = mfma16(af0, bfr, a1[n]);
    }
  }
  #pragma unroll
  for (int n = 0; n < 8; ++n) {
    float bv = bf1[w * 128 + n * 16 + fr];
    #pragma unroll
    for (int j = 0; j < 4; ++j)
      sH1[fg * 4 + j][w * 128 + n * 16 + fr] = (__bf16)gelu_f(a1[n][j] + bv);
  }
  __syncthreads();

  f32x4 a2[2];
  #pragma unroll
  for (int n = 0; n < 2; ++n) a2[n] = (f32x4){0.f, 0.f, 0.f, 0.f};
  #pragma unroll
  for (int kc = 0; kc < 16; ++kc) {
    int k0 = kc * 32;
    bf16x8 af0 = *(const bf16x8*)&sH1[fr][k0 + fg * 8];
    #pragma unroll
    for (int n = 0; n < 2; ++n) {
      bf16x8 bfr = *(const bf16x8*)(bw2 + (kc * 2 + n) * 512);
      a2[n] = mfma16(af0, bfr, a2[n]);
    }
  }
  #pragma unroll
  for (int n = 0; n < 2; ++n) {
    float bv = bf2[w * 32 + n * 16 + fr];
    #pragma unroll
    for (int j = 0; j < 4; ++j)
      sOut[fg * 4 + j][w * 32 + n * 16 + fr] = a2[n][j] + bv;
  }
  __syncthreads();

  {
    int r = tid >> 4, c0 = (tid & 15) * 8;
    long p = row0 + r;
    const float* xp = xin + p * HH + c0;
    float x[8];
    #pragma unroll
    for (int i = 0; i < 8; ++i) x[i] = xp[i] + sOut[r][c0 + i];
    float s = 0.f;
    #pragma unroll
    for (int i = 0; i < 8; ++i) s += x[i];
    s += __shfl_xor(s, 1); s += __shfl_xor(s, 2); s += __shfl_xor(s, 4); s += __shfl_xor(s, 8);
    float mean = s * (1.f / 128.f);
    float q = 0.f;
    #pragma unroll
    for (int i = 0; i < 8; ++i) { float e = x[i] - mean; q += e * e; }
    q += __shfl_xor(q, 1); q += __shfl_xor(q, 2); q += __shfl_xor(q, 4); q += __shfl_xor(q, 8);
    float rs = rsqrtf(q * (1.f / 128.f) + 1e-5f);
    float mv = maskV[p];
    float* op = out + p * HH + c0;
    #pragma unroll
    for (int i = 0; i < 8; ++i)
      op[i] = ((x[i] - mean) * rs * g2[c0 + i] + bn2[c0 + i]) * mv;
  }
}

extern "C" void kernel_launch(void* const* d_in, const int* in_sizes, int n_in,
                              void* d_out, int out_size, void* d_ws, size_t ws_size,
                              hipStream_t stream) {
  const float* hV    = (const float*)d_in[0];
  const float* hE    = (const float*)d_in[1];
  const float* maskV = (const float*)d_in[2];
  const float* maskE = (const float*)d_in[3];
  const float* w1    = (const float*)d_in[4];
  const float* b1    = (const float*)d_in[5];
  const float* w2    = (const float*)d_in[6];
  const float* b2    = (const float*)d_in[7];
  const float* w3    = (const float*)d_in[8];
  const float* b3    = (const float*)d_in[9];
  const float* g1    = (const float*)d_in[10];
  const float* bn1   = (const float*)d_in[11];
  const float* g2    = (const float*)d_in[12];
  const float* bn2   = (const float*)d_in[13];
  const float* wf1   = (const float*)d_in[14];
  const float* bf1   = (const float*)d_in[15];
  const float* wf2   = (const float*)d_in[16];
  const float* bf2   = (const float*)d_in[17];
  float* out = (float*)d_out;

  __bf16* wsb = (__bf16*)d_ws;                           // 212992 bf16 elems
  float* V1   = (float*)((char*)d_ws + 425984);          // [8192][128] f32
  float* hbuf = (float*)((char*)d_ws + 4620288);         // [8192][128] f32
  // requires ws_size >= 8,814,592 bytes

  prep_kernel<<<832, 256, 0, stream>>>(w1, w2, w3, wf1, wf2, wsb);
  v1_kernel<<<512, 128, 0, stream>>>(hV, w1, b1, V1);
  msg_kernel<<<8192, 256, 0, stream>>>(hE, hV, maskE,
                                       wsb, wsb + 49152, wsb + 65536, V1,
                                       b2, b3, g1, bn1, hbuf);
  ffn_kernel<<<512, 256, 0, stream>>>(hbuf, wsb + 81920, bf1, wsb + 147456, bf2,
                                      g2, bn2, maskV, out);
}